// Round 7
// baseline (65.736 us; speedup 1.0000x reference)
//
#include <hip/hip_runtime.h>

#define DIMS 128
#define KTOP 16
#define SMAX 2048     // max MAXG supported by top-k kernel
#define SLICE 32      // candidates staged per score block
#define SKP 132       // padded LDS row stride in floats
#define QCHUNK 8      // queries per compute pass (64 VGPRs of query fragments)

#define PIN4(f) asm volatile("" : "+v"((f).x), "+v"((f).y), "+v"((f).z), "+v"((f).w))

__device__ __forceinline__ float dot8(float4 a0, float4 a1, float4 b0, float4 b1) {
    return a0.x*b0.x + a0.y*b0.y + a0.z*b0.z + a0.w*b0.w
         + a1.x*b1.x + a1.y*b1.y + a1.z*b1.z + a1.w*b1.w;
}

__device__ __forceinline__ unsigned long long packsim(float v, int g) {
    unsigned u = __float_as_uint(v);
    u = (u & 0x80000000u) ? ~u : (u | 0x80000000u);
    return ((unsigned long long)u << 32) | (unsigned)(0xFFFFFFFFu - (unsigned)g);
}

// ---------------- Kernel 0: zero + bucket queries, single block ----------------
__global__ __launch_bounds__(1024)
void bucket_kernel(const int* __restrict__ hard_assign,
                   int* __restrict__ qcount, int* __restrict__ qlist, int B, int P)
{
    const int t = threadIdx.x;
    for (int i = t; i < P; i += 1024) qcount[i] = 0;
    __syncthreads();
    for (int b = t; b < B; b += 1024) {
        const int p = hard_assign[b];
        const int slot = atomicAdd(&qcount[p], 1);
        qlist[(size_t)p * B + slot] = b;
    }
}

// ---- Kernel 1: stage 32 normalized rows in LDS, score all queries of p ----
__global__ __launch_bounds__(256, 4)
void score_kernel(const float* __restrict__ query,
                  const float* __restrict__ keys,
                  const int*   __restrict__ cached_groups,
                  const int*   __restrict__ qcount,
                  const int*   __restrict__ qlist,
                  float* __restrict__ sims,
                  int B, int N, int MAXG, int nslice)
{
    const int p = blockIdx.x / nslice;
    const int s = blockIdx.x % nslice;
    const int cnt = qcount[p];
    if (cnt == 0) return;

    const int t   = threadIdx.x;
    const int sub = t & 15;     // D-slice lane (8 floats each)
    const int grp = t >> 4;     // candidate subgroup 0..15

    __shared__ int   s_g[SLICE];
    __shared__ float s_key[SLICE * SKP];

    const int base = s * SLICE;
    const int* gp = cached_groups + (size_t)p * MAXG;
    if (t < SLICE) s_g[t] = (base + t < MAXG) ? gp[base + t] : -1;
    __syncthreads();

    // phase 1: gather 2 rows per lane-group, L2-normalize, store to LDS
    {
        const int j0 = grp, j1 = 16 + grp;
        const int c0 = s_g[j0], c1 = s_g[j1];
        const int sf0 = c0 < 0 ? 0 : (c0 > N - 1 ? N - 1 : c0);
        const int sf1 = c1 < 0 ? 0 : (c1 > N - 1 ? N - 1 : c1);
        const float* kr0 = keys + (size_t)sf0 * DIMS + sub * 8;
        const float* kr1 = keys + (size_t)sf1 * DIMS + sub * 8;
        float4 a0 = *(const float4*)(kr0);
        float4 a1 = *(const float4*)(kr0 + 4);
        float4 b0 = *(const float4*)(kr1);
        float4 b1 = *(const float4*)(kr1 + 4);
        float ks0 = dot8(a0, a1, a0, a1);
        float ks1 = dot8(b0, b1, b0, b1);
        #pragma unroll
        for (int m = 1; m < 16; m <<= 1) {
            ks0 += __shfl_xor(ks0, m, 64);
            ks1 += __shfl_xor(ks1, m, 64);
        }
        const float i0 = 1.0f / fmaxf(sqrtf(ks0), 1e-12f);
        const float i1 = 1.0f / fmaxf(sqrtf(ks1), 1e-12f);
        a0.x *= i0; a0.y *= i0; a0.z *= i0; a0.w *= i0;
        a1.x *= i0; a1.y *= i0; a1.z *= i0; a1.w *= i0;
        b0.x *= i1; b0.y *= i1; b0.z *= i1; b0.w *= i1;
        b1.x *= i1; b1.y *= i1; b1.z *= i1; b1.w *= i1;
        *(float4*)&s_key[j0 * SKP + sub * 8]     = a0;
        *(float4*)&s_key[j0 * SKP + sub * 8 + 4] = a1;
        *(float4*)&s_key[j1 * SKP + sub * 8]     = b0;
        *(float4*)&s_key[j1 * SKP + sub * 8 + 4] = b1;
    }
    __syncthreads();
    // s_key/s_g are read-only below: the chunk loop is barrier-free.

    const int* ql = qlist + (size_t)p * B;
    const int nchunk = (cnt + QCHUNK - 1) / QCHUNK;

    for (int c = 0; c < nchunk; ++c) {
        const int qbase = c * QCHUNK;
        // 8 query fragments -> registers, pinned so the compiler cannot
        // rematerialize the loads inside the inner loop.
        float4 qf0[QCHUNK], qf1[QCHUNK];
        #pragma unroll
        for (int q = 0; q < QCHUNK; ++q) {
            const int ii = qbase + q;
            const int iic = (ii < cnt) ? ii : qbase;   // tail: dup (store-masked)
            const int sq = ql[iic];
            const float* qr = query + (size_t)sq * DIMS + sub * 8;
            qf0[q] = *(const float4*)(qr);
            qf1[q] = *(const float4*)(qr + 4);
        }
        #pragma unroll
        for (int q = 0; q < QCHUNK; ++q) { PIN4(qf0[q]); PIN4(qf1[q]); }

        // this lane's scatter-store target (lane sub<8 owns query slot sub)
        const int myii = qbase + (sub & 7);
        const int myb  = ql[(myii < cnt) ? myii : qbase];
        const bool mystore = (sub < QCHUNK) && (myii < cnt);

        #pragma unroll
        for (int it = 0; it < SLICE / 16; ++it) {
            const int j = it * 16 + grp;
            const float4 k0 = *(const float4*)&s_key[j * SKP + sub * 8];
            const float4 k1 = *(const float4*)&s_key[j * SKP + sub * 8 + 4];

            float v[QCHUNK];
            #pragma unroll
            for (int q = 0; q < QCHUNK; ++q) v[q] = dot8(qf0[q], qf1[q], k0, k1);

            // halving tree: 8 sets over 16 lanes -> lane sub (<8) owns q=sub
            float a[4];
            {
                const bool bit = sub & 1;
                #pragma unroll
                for (int jj = 0; jj < 4; ++jj) {
                    float send = bit ? v[2*jj] : v[2*jj+1];
                    float recv = __shfl_xor(send, 1, 64);
                    float keep = bit ? v[2*jj+1] : v[2*jj];
                    a[jj] = keep + recv;
                }
            }
            float cc[2];
            {
                const bool bit = (sub >> 1) & 1;
                #pragma unroll
                for (int jj = 0; jj < 2; ++jj) {
                    float send = bit ? a[2*jj] : a[2*jj+1];
                    float recv = __shfl_xor(send, 2, 64);
                    float keep = bit ? a[2*jj+1] : a[2*jj];
                    cc[jj] = keep + recv;
                }
            }
            float dd;
            {
                const bool bit = (sub >> 2) & 1;
                float send = bit ? cc[0] : cc[1];
                float recv = __shfl_xor(send, 4, 64);
                float keep = bit ? cc[1] : cc[0];
                dd = keep + recv;
            }
            const float e = dd + __shfl_xor(dd, 8, 64);

            if (mystore && base + j < MAXG) {
                const float val = (s_g[j] >= 0) ? e : -1.0e9f;
                sims[(size_t)myb * MAXG + base + j] = val;
            }
        }
    }
}

// ---------------- Kernel 2: top-16 per query + output gather ----------------
__global__ __launch_bounds__(256)
void topk_gather_kernel(const float* __restrict__ keys,
                        const float* __restrict__ vals,
                        const float* __restrict__ labels,
                        const int*   __restrict__ hard_assign,
                        const int*   __restrict__ cached_groups,
                        const int*   __restrict__ group_sizes,
                        const float* __restrict__ sims,
                        float* __restrict__ out,
                        int B, int MAXG)
{
    const int b = blockIdx.x, t = threadIdx.x;
    const int lane = t & 63, w = t >> 6;
    const int sub = t & 15, cg = t >> 4;

    __shared__ unsigned long long s_merge[64];
    __shared__ int s_wing[KTOP];

    const int p = hard_assign[b];
    const int grpsz = group_sizes[p];
    const bool normal = (grpsz >= KTOP);
    const int* gptr = cached_groups + (size_t)p * MAXG;
    const float* simrow = sims + (size_t)b * MAXG;

    // phase A: wave-local top-16 of 512 values, shuffle-only
    unsigned long long mk[SMAX / 256];
    #pragma unroll
    for (int j = 0; j < SMAX / 256; ++j) {
        const int g = w * (SMAX / 4) + j * 64 + lane;
        const float v = (g < MAXG) ? simrow[g] : -3.0e38f;
        mk[j] = packsim(v, g);
    }
    #pragma unroll 1
    for (int r = 0; r < KTOP; ++r) {
        unsigned long long m = mk[0];
        #pragma unroll
        for (int j = 1; j < SMAX / 256; ++j) m = (mk[j] > m) ? mk[j] : m;
        #pragma unroll
        for (int off = 1; off < 64; off <<= 1) {
            unsigned long long o = __shfl_xor(m, off, 64);
            m = (o > m) ? o : m;
        }
        if (lane == 0) s_merge[w * KTOP + r] = m;
        #pragma unroll
        for (int j = 0; j < SMAX / 256; ++j) if (mk[j] == m) mk[j] = 0ull;
    }
    __syncthreads();

    // phase B: wave 0 merges 64 survivors -> global top-16 in order
    if (w == 0) {
        unsigned long long u = s_merge[lane];
        #pragma unroll 1
        for (int r = 0; r < KTOP; ++r) {
            unsigned long long m = u;
            #pragma unroll
            for (int off = 1; off < 64; off <<= 1) {
                unsigned long long o = __shfl_xor(m, off, 64);
                m = (o > m) ? o : m;
            }
            if (lane == 0)
                s_wing[r] = (int)(0xFFFFFFFFu - (unsigned)(m & 0xFFFFFFFFull));
            if (u == m) u = 0ull;
        }
    }
    __syncthreads();

    // outputs: group cg handles winner #cg
    const int g    = s_wing[cg];
    const int cand = gptr[g];
    const int idx  = cand < 0 ? 0 : cand;

    const size_t BK = (size_t)B * KTOP;
    float* out_nk = out;
    float* out_nv = out + BK * DIMS;
    float* out_nl = out + 2 * BK * DIMS;
    float* out_id = out_nl + BK;

    const size_t od = ((size_t)b * KTOP + cg) * DIMS + sub * 8;
    if (normal) {
        const float* kr = keys + (size_t)idx * DIMS + sub * 8;
        const float* vr = vals + (size_t)idx * DIMS + sub * 8;
        *(float4*)(out_nk + od)     = *(const float4*)(kr);
        *(float4*)(out_nk + od + 4) = *(const float4*)(kr + 4);
        *(float4*)(out_nv + od)     = *(const float4*)(vr);
        *(float4*)(out_nv + od + 4) = *(const float4*)(vr + 4);
        if (sub == 0) {
            out_nl[(size_t)b * KTOP + cg] = labels[idx];
            out_id[(size_t)b * KTOP + cg] = (float)idx;
        }
    } else {
        const float4 z = make_float4(0.f, 0.f, 0.f, 0.f);
        *(float4*)(out_nk + od)     = z;
        *(float4*)(out_nk + od + 4) = z;
        *(float4*)(out_nv + od)     = z;
        *(float4*)(out_nv + od + 4) = z;
        if (sub == 0) {
            out_nl[(size_t)b * KTOP + cg] = 0.0f;
            out_id[(size_t)b * KTOP + cg] = 0.0f;
        }
    }
}

extern "C" void kernel_launch(void* const* d_in, const int* in_sizes, int n_in,
                              void* d_out, int out_size, void* d_ws, size_t ws_size,
                              hipStream_t stream) {
    const float* query  = (const float*)d_in[0];
    const float* keys   = (const float*)d_in[1];
    const float* vals   = (const float*)d_in[2];
    const float* labels = (const float*)d_in[3];
    const int* hard_assign   = (const int*)d_in[4];
    const int* cached_groups = (const int*)d_in[5];
    const int* group_sizes   = (const int*)d_in[6];

    const int B = in_sizes[0] / DIMS;
    const int N = in_sizes[1] / DIMS;
    const int P = in_sizes[6];
    const int MAXG = in_sizes[5] / P;
    const int nslice = (MAXG + SLICE - 1) / SLICE;

    float* sims  = (float*)d_ws;                                // B*MAXG floats
    int* qcount  = (int*)((char*)d_ws + (size_t)B * MAXG * 4);  // P ints
    int* qlist   = qcount + P;                                  // P*B ints

    bucket_kernel<<<1, 1024, 0, stream>>>(hard_assign, qcount, qlist, B, P);

    score_kernel<<<P * nslice, 256, 0, stream>>>(
        query, keys, cached_groups, qcount, qlist, sims, B, N, MAXG, nslice);

    topk_gather_kernel<<<B, 256, 0, stream>>>(
        keys, vals, labels, hard_assign, cached_groups, group_sizes, sims,
        (float*)d_out, B, MAXG);
}

// Round 8
// 62.873 us; speedup vs baseline: 1.0455x; 1.0455x over previous
//
#include <hip/hip_runtime.h>

#define DIMS 128
#define KTOP 16
#define SMAX 2048     // max MAXG supported by top-k kernel
#define SLICE 32      // candidates staged per score block
#define SKP 132       // padded LDS row stride in floats
#define QCHUNK 8      // queries per register pass
#define QPASS 16      // queries staged in LDS per pass

#define PIN4(f) asm volatile("" : "+v"((f).x), "+v"((f).y), "+v"((f).z), "+v"((f).w))

__device__ __forceinline__ float dot8(float4 a0, float4 a1, float4 b0, float4 b1) {
    return a0.x*b0.x + a0.y*b0.y + a0.z*b0.z + a0.w*b0.w
         + a1.x*b1.x + a1.y*b1.y + a1.z*b1.z + a1.w*b1.w;
}

__device__ __forceinline__ unsigned long long packsim(float v, int g) {
    unsigned u = __float_as_uint(v);
    u = (u & 0x80000000u) ? ~u : (u | 0x80000000u);
    return ((unsigned long long)u << 32) | (unsigned)(0xFFFFFFFFu - (unsigned)g);
}

// ---------------- Kernel 0: zero + bucket queries, single block ----------------
__global__ __launch_bounds__(1024)
void bucket_kernel(const int* __restrict__ hard_assign,
                   int* __restrict__ qcount, int* __restrict__ qlist, int B, int P)
{
    const int t = threadIdx.x;
    for (int i = t; i < P; i += 1024) qcount[i] = 0;
    __syncthreads();
    for (int b = t; b < B; b += 1024) {
        const int p = hard_assign[b];
        const int slot = atomicAdd(&qcount[p], 1);
        qlist[(size_t)p * B + slot] = b;
    }
}

// ---- Kernel 1: stage 32 normalized keys + 16 queries in LDS, score ----
__global__ __launch_bounds__(256, 4)
void score_kernel(const float* __restrict__ query,
                  const float* __restrict__ keys,
                  const int*   __restrict__ cached_groups,
                  const int*   __restrict__ qcount,
                  const int*   __restrict__ qlist,
                  float* __restrict__ sims,
                  int B, int N, int MAXG, int nslice)
{
    const int p = blockIdx.x / nslice;
    const int s = blockIdx.x % nslice;
    const int cnt = qcount[p];
    if (cnt == 0) return;

    const int t   = threadIdx.x;
    const int sub = t & 15;     // D-slice lane (8 floats each)
    const int grp = t >> 4;     // candidate / query-slot group 0..15

    __shared__ int   s_g[SLICE];
    __shared__ float s_key[SLICE * SKP];
    __shared__ float s_q[QPASS * SKP];

    const int base = s * SLICE;
    const int* gp = cached_groups + (size_t)p * MAXG;
    if (t < SLICE) s_g[t] = (base + t < MAXG) ? gp[base + t] : -1;
    __syncthreads();

    // stage keys: 2 rows per lane-group, L2-normalize, store to LDS
    {
        const int j0 = grp, j1 = 16 + grp;
        const int c0 = s_g[j0], c1 = s_g[j1];
        const int sf0 = c0 < 0 ? 0 : (c0 > N - 1 ? N - 1 : c0);
        const int sf1 = c1 < 0 ? 0 : (c1 > N - 1 ? N - 1 : c1);
        const float* kr0 = keys + (size_t)sf0 * DIMS + sub * 8;
        const float* kr1 = keys + (size_t)sf1 * DIMS + sub * 8;
        float4 a0 = *(const float4*)(kr0);
        float4 a1 = *(const float4*)(kr0 + 4);
        float4 b0 = *(const float4*)(kr1);
        float4 b1 = *(const float4*)(kr1 + 4);
        float ks0 = dot8(a0, a1, a0, a1);
        float ks1 = dot8(b0, b1, b0, b1);
        #pragma unroll
        for (int m = 1; m < 16; m <<= 1) {
            ks0 += __shfl_xor(ks0, m, 64);
            ks1 += __shfl_xor(ks1, m, 64);
        }
        const float i0 = 1.0f / fmaxf(sqrtf(ks0), 1e-12f);
        const float i1 = 1.0f / fmaxf(sqrtf(ks1), 1e-12f);
        a0.x *= i0; a0.y *= i0; a0.z *= i0; a0.w *= i0;
        a1.x *= i0; a1.y *= i0; a1.z *= i0; a1.w *= i0;
        b0.x *= i1; b0.y *= i1; b0.z *= i1; b0.w *= i1;
        b1.x *= i1; b1.y *= i1; b1.z *= i1; b1.w *= i1;
        *(float4*)&s_key[j0 * SKP + sub * 8]     = a0;
        *(float4*)&s_key[j0 * SKP + sub * 8 + 4] = a1;
        *(float4*)&s_key[j1 * SKP + sub * 8]     = b0;
        *(float4*)&s_key[j1 * SKP + sub * 8 + 4] = b1;
    }

    const int* ql = qlist + (size_t)p * B;

    for (int qp = 0; qp < cnt; qp += QPASS) {
        // stage up to 16 query rows: group grp loads slot grp (coalesced 512B rows)
        __syncthreads();    // first pass: covers s_key too; later: protect overwrite
        {
            const int ii = qp + grp;
            const int sq = ql[(ii < cnt) ? ii : (cnt - 1)];   // dup tail, store-masked
            const float* qr = query + (size_t)sq * DIMS + sub * 8;
            const float4 a0 = *(const float4*)(qr);
            const float4 a1 = *(const float4*)(qr + 4);
            *(float4*)&s_q[grp * SKP + sub * 8]     = a0;
            *(float4*)&s_q[grp * SKP + sub * 8 + 4] = a1;
        }
        __syncthreads();

        const int pcnt = (cnt - qp < QPASS) ? (cnt - qp) : QPASS;

        for (int c = 0; c * QCHUNK < pcnt; ++c) {
            // 8 query fragments from LDS -> registers (cheap even if rematerialized)
            float4 qf0[QCHUNK], qf1[QCHUNK];
            #pragma unroll
            for (int q = 0; q < QCHUNK; ++q) {
                const int slot = c * QCHUNK + q;
                qf0[q] = *(const float4*)&s_q[slot * SKP + sub * 8];
                qf1[q] = *(const float4*)&s_q[slot * SKP + sub * 8 + 4];
            }
            #pragma unroll
            for (int q = 0; q < QCHUNK; ++q) { PIN4(qf0[q]); PIN4(qf1[q]); }

            // this lane's scatter-store target (lane sub<8 owns query slot sub)
            const int myii = qp + c * QCHUNK + (sub & 7);
            const int myb  = ql[(myii < cnt) ? myii : 0];
            const bool mystore = (sub < QCHUNK) && (myii < cnt);

            #pragma unroll
            for (int it = 0; it < SLICE / 16; ++it) {
                const int j = it * 16 + grp;
                const float4 k0 = *(const float4*)&s_key[j * SKP + sub * 8];
                const float4 k1 = *(const float4*)&s_key[j * SKP + sub * 8 + 4];

                float v[QCHUNK];
                #pragma unroll
                for (int q = 0; q < QCHUNK; ++q) v[q] = dot8(qf0[q], qf1[q], k0, k1);

                // halving tree: 8 sets over 16 lanes -> lane sub (<8) owns q=sub
                float a[4];
                {
                    const bool bit = sub & 1;
                    #pragma unroll
                    for (int jj = 0; jj < 4; ++jj) {
                        float send = bit ? v[2*jj] : v[2*jj+1];
                        float recv = __shfl_xor(send, 1, 64);
                        float keep = bit ? v[2*jj+1] : v[2*jj];
                        a[jj] = keep + recv;
                    }
                }
                float cc[2];
                {
                    const bool bit = (sub >> 1) & 1;
                    #pragma unroll
                    for (int jj = 0; jj < 2; ++jj) {
                        float send = bit ? a[2*jj] : a[2*jj+1];
                        float recv = __shfl_xor(send, 2, 64);
                        float keep = bit ? a[2*jj+1] : a[2*jj];
                        cc[jj] = keep + recv;
                    }
                }
                float dd;
                {
                    const bool bit = (sub >> 2) & 1;
                    float send = bit ? cc[0] : cc[1];
                    float recv = __shfl_xor(send, 4, 64);
                    float keep = bit ? cc[1] : cc[0];
                    dd = keep + recv;
                }
                const float e = dd + __shfl_xor(dd, 8, 64);

                if (mystore && base + j < MAXG) {
                    const float val = (s_g[j] >= 0) ? e : -1.0e9f;
                    sims[(size_t)myb * MAXG + base + j] = val;
                }
            }
        }
    }
}

// ---------------- Kernel 2: top-16 per query + output gather ----------------
__global__ __launch_bounds__(256)
void topk_gather_kernel(const float* __restrict__ keys,
                        const float* __restrict__ vals,
                        const float* __restrict__ labels,
                        const int*   __restrict__ hard_assign,
                        const int*   __restrict__ cached_groups,
                        const int*   __restrict__ group_sizes,
                        const float* __restrict__ sims,
                        float* __restrict__ out,
                        int B, int MAXG)
{
    const int b = blockIdx.x, t = threadIdx.x;
    const int lane = t & 63, w = t >> 6;
    const int sub = t & 15, cg = t >> 4;

    __shared__ unsigned long long s_merge[64];
    __shared__ int s_wing[KTOP];

    const int p = hard_assign[b];
    const int grpsz = group_sizes[p];
    const bool normal = (grpsz >= KTOP);
    const int* gptr = cached_groups + (size_t)p * MAXG;
    const float* simrow = sims + (size_t)b * MAXG;

    // phase A: wave-local top-16 of 512 values, shuffle-only
    unsigned long long mk[SMAX / 256];
    #pragma unroll
    for (int j = 0; j < SMAX / 256; ++j) {
        const int g = w * (SMAX / 4) + j * 64 + lane;
        const float v = (g < MAXG) ? simrow[g] : -3.0e38f;
        mk[j] = packsim(v, g);
    }
    #pragma unroll 1
    for (int r = 0; r < KTOP; ++r) {
        unsigned long long m = mk[0];
        #pragma unroll
        for (int j = 1; j < SMAX / 256; ++j) m = (mk[j] > m) ? mk[j] : m;
        #pragma unroll
        for (int off = 1; off < 64; off <<= 1) {
            unsigned long long o = __shfl_xor(m, off, 64);
            m = (o > m) ? o : m;
        }
        if (lane == 0) s_merge[w * KTOP + r] = m;
        #pragma unroll
        for (int j = 0; j < SMAX / 256; ++j) if (mk[j] == m) mk[j] = 0ull;
    }
    __syncthreads();

    // phase B: wave 0 merges 64 survivors -> global top-16 in order
    if (w == 0) {
        unsigned long long u = s_merge[lane];
        #pragma unroll 1
        for (int r = 0; r < KTOP; ++r) {
            unsigned long long m = u;
            #pragma unroll
            for (int off = 1; off < 64; off <<= 1) {
                unsigned long long o = __shfl_xor(m, off, 64);
                m = (o > m) ? o : m;
            }
            if (lane == 0)
                s_wing[r] = (int)(0xFFFFFFFFu - (unsigned)(m & 0xFFFFFFFFull));
            if (u == m) u = 0ull;
        }
    }
    __syncthreads();

    // outputs: group cg handles winner #cg
    const int g    = s_wing[cg];
    const int cand = gptr[g];
    const int idx  = cand < 0 ? 0 : cand;

    const size_t BK = (size_t)B * KTOP;
    float* out_nk = out;
    float* out_nv = out + BK * DIMS;
    float* out_nl = out + 2 * BK * DIMS;
    float* out_id = out_nl + BK;

    const size_t od = ((size_t)b * KTOP + cg) * DIMS + sub * 8;
    if (normal) {
        const float* kr = keys + (size_t)idx * DIMS + sub * 8;
        const float* vr = vals + (size_t)idx * DIMS + sub * 8;
        *(float4*)(out_nk + od)     = *(const float4*)(kr);
        *(float4*)(out_nk + od + 4) = *(const float4*)(kr + 4);
        *(float4*)(out_nv + od)     = *(const float4*)(vr);
        *(float4*)(out_nv + od + 4) = *(const float4*)(vr + 4);
        if (sub == 0) {
            out_nl[(size_t)b * KTOP + cg] = labels[idx];
            out_id[(size_t)b * KTOP + cg] = (float)idx;
        }
    } else {
        const float4 z = make_float4(0.f, 0.f, 0.f, 0.f);
        *(float4*)(out_nk + od)     = z;
        *(float4*)(out_nk + od + 4) = z;
        *(float4*)(out_nv + od)     = z;
        *(float4*)(out_nv + od + 4) = z;
        if (sub == 0) {
            out_nl[(size_t)b * KTOP + cg] = 0.0f;
            out_id[(size_t)b * KTOP + cg] = 0.0f;
        }
    }
}

extern "C" void kernel_launch(void* const* d_in, const int* in_sizes, int n_in,
                              void* d_out, int out_size, void* d_ws, size_t ws_size,
                              hipStream_t stream) {
    const float* query  = (const float*)d_in[0];
    const float* keys   = (const float*)d_in[1];
    const float* vals   = (const float*)d_in[2];
    const float* labels = (const float*)d_in[3];
    const int* hard_assign   = (const int*)d_in[4];
    const int* cached_groups = (const int*)d_in[5];
    const int* group_sizes   = (const int*)d_in[6];

    const int B = in_sizes[0] / DIMS;
    const int N = in_sizes[1] / DIMS;
    const int P = in_sizes[6];
    const int MAXG = in_sizes[5] / P;
    const int nslice = (MAXG + SLICE - 1) / SLICE;

    float* sims  = (float*)d_ws;                                // B*MAXG floats
    int* qcount  = (int*)((char*)d_ws + (size_t)B * MAXG * 4);  // P ints
    int* qlist   = qcount + P;                                  // P*B ints

    bucket_kernel<<<1, 1024, 0, stream>>>(hard_assign, qcount, qlist, B, P);

    score_kernel<<<P * nslice, 256, 0, stream>>>(
        query, keys, cached_groups, qcount, qlist, sims, B, N, MAXG, nslice);

    topk_gather_kernel<<<B, 256, 0, stream>>>(
        keys, vals, labels, hard_assign, cached_groups, group_sizes, sims,
        (float*)d_out, B, MAXG);
}